// Round 5
// baseline (106.715 us; speedup 1.0000x reference)
//
#include <hip/hip_runtime.h>

#define HH 512
#define WW 1024
#define NC 19
#define HWP (HH * WW)
#define NB 4
#define NREP 4
#define NXCD 8
#define IGNORE_IDX 255

typedef float f2v __attribute__((ext_vector_type(2)));

// Load + exp stage for one channel-half. All indices compile-time (rule #20).
template<int C0, int NCH>
__device__ __forceinline__ void half_load(
    const float* __restrict__ tb, const float* __restrict__ pb,
    int pix, int spix, float (&te)[10], float (&pe)[10],
    float& ts, float& ps)
{
    ts = 0.f; ps = 0.f;
#pragma unroll
    for (int i = 0; i < NCH; ++i) {
        te[i] = __expf(__builtin_nontemporal_load(&tb[(size_t)(C0 + i) * HWP + pix]));
        ts += te[i];
    }
#pragma unroll
    for (int i = 0; i < NCH; ++i) {
        pe[i] = __expf(pb[(size_t)(C0 + i) * HWP + spix]);
        ps += pe[i];
    }
}

template<int NCH>
__device__ __forceinline__ void half_acc(
    const float (&te)[10], const float (&pe)[10],
    float tinv, float pinv, float (&accn)[10], float (&accd)[10])
{
#pragma unroll
    for (int i = 0; i < NCH; ++i) {
        const float t = te[i] * tinv;
        const float p = pe[i] * pinv;
        const float pt = p * t;
        accn[i] += pt;
        accd[i] += p + t - pt;
    }
}

// ws layout: float acc[NREP][NB][NC][2]  (num, den)
__global__ __launch_bounds__(256) void tc_main(
    const float* __restrict__ preds,
    const float* __restrict__ targets,
    const float* __restrict__ flow,
    const int* __restrict__ labels,
    float* __restrict__ acc)
{
    const int tid   = threadIdx.x;
    const int w     = tid >> 6;
    const int lane  = tid & 63;
    const int chalf = w >> 1;                   // 0: ch 0-9, 1: ch 10-18
    const int pl    = ((w & 1) << 6) | lane;    // 0..127 pixel slot

    // XCD-chunked swizzle (R4 win: keeps overlapping gather rows in one L2)
    const int nwg   = gridDim.x;                // 2048
    const int chunk = nwg / NXCD;               // 256
    const int phys  = blockIdx.x;
    const int logical = (phys % NXCD) * chunk + phys / NXCD;

    const int blocks_per_img = nwg / NB;        // 512
    const int b   = logical / blocks_per_img;
    const int blk = logical % blocks_per_img;

    const float* tb = targets + (size_t)b * NC * HWP;
    const float* pb = preds   + (size_t)b * NC * HWP;
    const f2v*   fb = (const f2v*)(flow + (size_t)b * HWP * 2);
    const int*   lb = labels  + (size_t)b * HWP;

    const int per_block = HWP / blocks_per_img; // 1024 (one image row)
    const int base  = blk * per_block;
    const int nIter = per_block / 128;          // 8

    __shared__ float2 part[2][2][128];          // [buf][chalf][pl] = {tsum, psum}
    __shared__ float  sred[4][10][2];

    float accn[10], accd[10];
#pragma unroll
    for (int i = 0; i < 10; ++i) { accn[i] = 0.f; accd[i] = 0.f; }

    for (int it = 0; it < nIter; ++it) {
        const int pix = base + it * 128 + pl;
        const int y = pix >> 10;                // WW = 1024
        const int x = pix & (WW - 1);

        const f2v f = __builtin_nontemporal_load(&fb[pix]);
        const int rx = (int)rintf((float)x + f.x);  // round-half-even == jnp.round
        const int ry = (int)rintf((float)y + f.y);
        const bool valid = (rx >= 0) && (rx < WW) && (ry >= 0) && (ry < HH);
        const int spix = min(max(ry, 0), HH - 1) * WW + min(max(rx, 0), WW - 1);
        const bool keep = (__builtin_nontemporal_load(&lb[pix]) != IGNORE_IDX);

        float te[10], pe[10], ts, ps;
        if (chalf == 0) half_load<0, 10>(tb, pb, pix, spix, te, pe, ts, ps);
        else            half_load<10, 9>(tb, pb, pix, spix, te, pe, ts, ps);

        const int buf = it & 1;
        part[buf][chalf][pl] = make_float2(ts, ps);
        __syncthreads();
        const float2 o = part[buf][1 - chalf][pl];

        const float tinv = keep  ? (1.0f / (ts + o.x)) : 0.0f;
        const float pinv = valid ? (1.0f / (ps + o.y)) : 0.0f;

        if (chalf == 0) half_acc<10>(te, pe, tinv, pinv, accn, accd);
        else            half_acc<9>(te, pe, tinv, pinv, accn, accd);
    }

    // wave shuffle reduce (element 9 of chalf-1 waves stays 0 — harmless)
#pragma unroll
    for (int i = 0; i < 10; ++i) {
        for (int off = 32; off > 0; off >>= 1) {
            accn[i] += __shfl_xor(accn[i], off);
            accd[i] += __shfl_xor(accd[i], off);
        }
    }
    if (lane == 0) {
#pragma unroll
        for (int i = 0; i < 10; ++i) {
            sred[w][i][0] = accn[i];
            sred[w][i][1] = accd[i];
        }
    }
    __syncthreads();
    if (tid < NC * 2) {
        const int c  = tid >> 1;
        const int wh = tid & 1;
        float v;
        if (c < 10) v = sred[0][c][wh] + sred[1][c][wh];
        else        v = sred[2][c - 10][wh] + sred[3][c - 10][wh];
        const int rep = phys & (NREP - 1);
        atomicAdd(&acc[(((size_t)rep * NB + b) * NC + c) * 2 + wh], v);
    }
}

__global__ void tc_final(const float* __restrict__ acc, float* __restrict__ out)
{
    if (threadIdx.x == 0 && blockIdx.x == 0) {
        float total = 0.f;
        for (int b = 0; b < NB; ++b) {
            float m = 0.f;
            for (int c = 0; c < NC; ++c) {
                float n = 0.f, d = 0.f;
                for (int r = 0; r < NREP; ++r) {
                    n += acc[(((size_t)r * NB + b) * NC + c) * 2 + 0];
                    d += acc[(((size_t)r * NB + b) * NC + c) * 2 + 1];
                }
                m += n / d;
            }
            total += 1.0f - m / (float)NC;
        }
        out[0] = total / (float)NB;
    }
}

extern "C" void kernel_launch(void* const* d_in, const int* in_sizes, int n_in,
                              void* d_out, int out_size, void* d_ws, size_t ws_size,
                              hipStream_t stream) {
    const float* preds   = (const float*)d_in[0];
    const float* targets = (const float*)d_in[1];
    const float* flow    = (const float*)d_in[2];
    const int*   labels  = (const int*)d_in[3];
    float* acc = (float*)d_ws;

    hipMemsetAsync(acc, 0, (size_t)NREP * NB * NC * 2 * sizeof(float), stream);

    tc_main<<<2048, 256, 0, stream>>>(preds, targets, flow, labels, acc);
    tc_final<<<1, 64, 0, stream>>>(acc, (float*)d_out);
}